// Round 13
// baseline (74.791 us; speedup 1.0000x reference)
//
#include <hip/hip_runtime.h>
#include <hip/hip_bf16.h>
#include <math.h>

#define BATCH 8
#define NPTS  256
#define HDIM  128
#define TOTAL (BATCH * NPTS)   // 2048
#define PRE_SCALE 0.25f        // tau = pre/4
#define DEG   10               // even poly degree for G(tau)=E(4*tau)
#define NQ    11               // q = 0..10
#define KDIM  (HDIM * NQ)      // 1408 = GEMM K
#define MROWS (3 * NPTS)       // 768 stacked feature rows (X0,X1,X2)

typedef __attribute__((ext_vector_type(8))) short short8;
typedef __attribute__((ext_vector_type(4))) float f32x4;

struct QC { float v[3][NQ][NQ]; };   // qc[n][q][p] = Pn[p+q]*C(p+q,p)

// ---------------------------------------------------------------------------
// Kernel 1: projections + lambdas + GEMM feature build + out-zero.
//   u = s*(h@Wa)[t,c], v = s*((h@Wb)[t,c]+b1), w = s*wd_c
//   Uf[b][n*256+j][c*11+q] = alpha_n(c) * Q_n,q(u)   (bf16)
//      where Q_n,q(u) = G_n^(q)(u)/q!  (precomputed monomial coeffs qc)
//      alpha = { W2, W2*w, W2*w^2/2 }
//   Vf[b][i][c*11+q] = v^q                            (bf16)
//   lamA/lamB/lamD = exact linear (odd) part of silu; pos4 packed.
// ---------------------------------------------------------------------------
__global__ __launch_bounds__(HDIM) void evh_prep_kernel(
    const float* __restrict__ h, const float* __restrict__ W1,
    const float* __restrict__ b1, const float* __restrict__ W2,
    const float* __restrict__ pos,
    __hip_bfloat16* __restrict__ Uf, __hip_bfloat16* __restrict__ Vf,
    float4* __restrict__ pos4,
    float* __restrict__ lamA, float* __restrict__ lamB,
    float* __restrict__ lamD, float* __restrict__ out, QC qc)
{
    __shared__ float hrow[HDIM];
    __shared__ float sA[2], sB[2], sD[2];
    const int t = blockIdx.x;
    const int c = threadIdx.x;
    const int wv = c >> 6, ln = c & 63;
    const int b = t >> 8, jj = t & 255;
    hrow[c] = h[t * HDIM + c];
    const float w2c = W2[c];
    const float wdc = W1[2 * HDIM * HDIM + c];
    if (c < 3) out[t * 3 + c] = 0.f;
    if (c == 0)
        pos4[t] = make_float4(pos[t * 3], pos[t * 3 + 1], pos[t * 3 + 2], 0.f);
    __syncthreads();

    float a = 0.f, bsum = 0.f;
#pragma unroll 8
    for (int k = 0; k < HDIM; ++k) {
        const float hv = hrow[k];
        a    = fmaf(hv, W1[k * HDIM + c], a);
        bsum = fmaf(hv, W1[(HDIM + k) * HDIM + c], bsum);
    }
    const float bb = bsum + b1[c];

    // feature build
    const float u = a * PRE_SCALE;
    const float v = bb * PRE_SCALE;
    const float w = wdc * PRE_SCALE;
    const float alph[3] = { w2c, w2c * w, 0.5f * w2c * w * w };
    for (int n = 0; n < 3; ++n) {
        __hip_bfloat16* dst =
            Uf + ((size_t)((b * 3 + n) * NPTS + jj)) * KDIM + c * NQ;
        const float an = alph[n];
        for (int q = 0; q < NQ; ++q) {
            const int dp = DEG - q;
            float r = qc.v[n][q][dp];
            for (int p = dp - 1; p >= 0; --p) r = fmaf(r, u, qc.v[n][q][p]);
            dst[q] = __float2bfloat16(an * r);
        }
    }
    {
        __hip_bfloat16* vdst = Vf + ((size_t)(b * NPTS + jj)) * KDIM + c * NQ;
        float vp = 1.f;
        for (int q = 0; q < NQ; ++q) { vdst[q] = __float2bfloat16(vp); vp *= v; }
    }

    // exact linear-part lambdas (wave shuffles)
    float va = w2c * a, vb = w2c * bb;
#pragma unroll
    for (int off = 32; off >= 1; off >>= 1) {
        va += __shfl_xor(va, off, 64);
        vb += __shfl_xor(vb, off, 64);
    }
    if (ln == 0) { sA[wv] = va; sB[wv] = vb; }
    __syncthreads();
    if (c == 0) {
        lamA[t] = 0.5f * (sA[0] + sA[1]);
        lamB[t] = 0.5f * (sB[0] + sB[1]);
    }
    if (t == 0) {  // block-uniform branch
        float vd = w2c * wdc;
#pragma unroll
        for (int off = 32; off >= 1; off >>= 1) vd += __shfl_xor(vd, off, 64);
        if (ln == 0) sD[wv] = vd;
        __syncthreads();
        if (c == 0) lamD[0] = 0.5f * (sD[0] + sD[1]);
    }
}

// ---------------------------------------------------------------------------
// Kernel 2: batched MFMA GEMM. X[b][n][i][j] = sum_k Uf[b][n*256+j][k]*Vf[b][i][k]
// 384 blocks (batch = blk&7 -> XCD-local operands), 64x64 tile per block,
// 4 waves x (32x32 via 2x2 16x16x32 bf16 frags), K-loop 44 with 1-deep
// register prefetch. C written transposed into X[b][n][i][j] (float4 per frag).
// ---------------------------------------------------------------------------
__global__ __launch_bounds__(256) void evh_gemm_kernel(
    const __hip_bfloat16* __restrict__ Uf, const __hip_bfloat16* __restrict__ Vf,
    float* __restrict__ X)
{
    const int blk = blockIdx.x;
    const int b    = blk & 7;
    const int tile = blk >> 3;            // 0..47
    const int tm   = tile % 12;           // 64-row tile of M=768
    const int tn   = tile / 12;           // 64-col tile of N=256
    const int tid  = threadIdx.x;
    const int wave = tid >> 6, lane = tid & 63;
    const int mrow = lane & 15, kb = lane >> 4;

    const int m0 = tm * 64 + (wave >> 1) * 32;   // feature-row base
    const int n0 = tn * 64 + (wave & 1) * 32;    // i base

    const __hip_bfloat16* __restrict__ Ub = Uf + (size_t)b * MROWS * KDIM;
    const __hip_bfloat16* __restrict__ Vb = Vf + (size_t)b * NPTS * KDIM;

    f32x4 acc[2][2] = {};

#define LDA(MM, KO) (*reinterpret_cast<const short8*>(Ub + (size_t)(MM) * KDIM + (KO)))
#define LDB(NN, KO) (*reinterpret_cast<const short8*>(Vb + (size_t)(NN) * KDIM + (KO)))

    int koff = kb * 8;
    short8 A0 = LDA(m0 + mrow, koff),      A1 = LDA(m0 + 16 + mrow, koff);
    short8 B0 = LDB(n0 + mrow, koff),      B1 = LDB(n0 + 16 + mrow, koff);

    for (int kk = 0; kk < KDIM / 32; ++kk) {
        short8 nA0, nA1, nB0, nB1;
        if (kk + 1 < KDIM / 32) {
            const int nk = (kk + 1) * 32 + kb * 8;
            nA0 = LDA(m0 + mrow, nk);      nA1 = LDA(m0 + 16 + mrow, nk);
            nB0 = LDB(n0 + mrow, nk);      nB1 = LDB(n0 + 16 + mrow, nk);
        }
        acc[0][0] = __builtin_amdgcn_mfma_f32_16x16x32_bf16(A0, B0, acc[0][0], 0, 0, 0);
        acc[0][1] = __builtin_amdgcn_mfma_f32_16x16x32_bf16(A0, B1, acc[0][1], 0, 0, 0);
        acc[1][0] = __builtin_amdgcn_mfma_f32_16x16x32_bf16(A1, B0, acc[1][0], 0, 0, 0);
        acc[1][1] = __builtin_amdgcn_mfma_f32_16x16x32_bf16(A1, B1, acc[1][1], 0, 0, 0);
        A0 = nA0; A1 = nA1; B0 = nB0; B1 = nB1;
    }
#undef LDA
#undef LDB

    // C-write transposed: row m -> (nfeat = m>>8, j = m&255), col -> i.
#pragma unroll
    for (int fm = 0; fm < 2; ++fm) {
#pragma unroll
        for (int fn = 0; fn < 2; ++fn) {
            const int mbase = m0 + fm * 16 + (lane >> 4) * 4;  // 4-aligned
            const int i     = n0 + fn * 16 + (lane & 15);
            const int nfeat = mbase >> 8;
            const int j0    = mbase & 255;
            float* dst = X + ((size_t)((b * 3 + nfeat) * NPTS + i)) * NPTS + j0;
            *reinterpret_cast<float4*>(dst) =
                *reinterpret_cast<float4*>(&acc[fm][fn]);
        }
    }
}

// ---------------------------------------------------------------------------
// Kernel 3: combine + v-reduction. Block = (b, i-pair). 1024 blocks x 256
// threads = j. coeff = lin(lam) + b2 + X0 + d*X1 + d^2*X2; v += coeff*diff;
// wave-shuffle reduce + atomicAdd.
// ---------------------------------------------------------------------------
__global__ __launch_bounds__(256) void evh_comb_kernel(
    const float* __restrict__ X, const float4* __restrict__ pos4,
    const float* __restrict__ lamA, const float* __restrict__ lamB,
    const float* __restrict__ lamD, const float* __restrict__ b2,
    float* __restrict__ out)
{
    const int blk = blockIdx.x;                 // 0..1023
    const int b   = blk >> 7;
    const int i0  = (blk & 127) * 2;
    const int tid = threadIdx.x;                // = j
    const int brow = b * NPTS;
    const int row_j = brow + tid;

    const float4 pj  = pos4[row_j];
    const float4 pi0 = pos4[brow + i0];
    const float4 pi1 = pos4[brow + i0 + 1];
    const float dx0 = pj.x - pi0.x, dy0 = pj.y - pi0.y, dz0 = pj.z - pi0.z;
    const float dx1 = pj.x - pi1.x, dy1 = pj.y - pi1.y, dz1 = pj.z - pi1.z;
    const float d0 = sqrtf(dx0 * dx0 + dy0 * dy0 + dz0 * dz0);
    const float d1 = sqrtf(dx1 * dx1 + dy1 * dy1 + dz1 * dz1);

    const size_t xb = (size_t)(b * 3) * NPTS * NPTS;
    const float x00 = X[xb + (size_t)(0 * NPTS + i0)     * NPTS + tid];
    const float x01 = X[xb + (size_t)(0 * NPTS + i0 + 1) * NPTS + tid];
    const float x10 = X[xb + (size_t)(1 * NPTS + i0)     * NPTS + tid];
    const float x11 = X[xb + (size_t)(1 * NPTS + i0 + 1) * NPTS + tid];
    const float x20 = X[xb + (size_t)(2 * NPTS + i0)     * NPTS + tid];
    const float x21 = X[xb + (size_t)(2 * NPTS + i0 + 1) * NPTS + tid];

    const float la = lamA[row_j];
    const float ld = lamD[0];
    const float bv = b2[0];
    const float c0 = la + lamB[brow + i0]     + d0 * ld + bv
                     + x00 + d0 * x10 + d0 * d0 * x20;
    const float c1 = la + lamB[brow + i0 + 1] + d1 * ld + bv
                     + x01 + d1 * x11 + d1 * d1 * x21;

    const int wave = tid >> 6, lane = tid & 63;
    float v0x = c0 * dx0, v0y = c0 * dy0, v0z = c0 * dz0;
    float v1x = c1 * dx1, v1y = c1 * dy1, v1z = c1 * dz1;
#pragma unroll
    for (int off = 32; off >= 1; off >>= 1) {
        v0x += __shfl_xor(v0x, off, 64);
        v0y += __shfl_xor(v0y, off, 64);
        v0z += __shfl_xor(v0z, off, 64);
        v1x += __shfl_xor(v1x, off, 64);
        v1y += __shfl_xor(v1y, off, 64);
        v1z += __shfl_xor(v1z, off, 64);
    }
    __shared__ float vsh[4][6];
    if (lane == 0) {
        vsh[wave][0] = v0x; vsh[wave][1] = v0y; vsh[wave][2] = v0z;
        vsh[wave][3] = v1x; vsh[wave][4] = v1y; vsh[wave][5] = v1z;
    }
    __syncthreads();
    if (tid < 6) {
        const float val = vsh[0][tid] + vsh[1][tid] + vsh[2][tid] + vsh[3][tid];
        const int s = tid / 3, comp = tid % 3;
        atomicAdd(&out[(brow + i0 + s) * 3 + comp], val);
    }
}

extern "C" void kernel_launch(void* const* d_in, const int* in_sizes, int n_in,
                              void* d_out, int out_size, void* d_ws, size_t ws_size,
                              hipStream_t stream) {
    const float* h   = (const float*)d_in[0];
    const float* pos = (const float*)d_in[1];
    const float* W1  = (const float*)d_in[3];
    const float* b1  = (const float*)d_in[4];
    const float* W2  = (const float*)d_in[5];
    const float* b2  = (const float*)d_in[6];
    float* out = (float*)d_out;

    // workspace layout (~29.5 MB)
    float* X = (float*)d_ws;                               // 8*3*256*256 f32
    float4* pos4 = (float4*)(X + (size_t)BATCH * 3 * NPTS * NPTS);
    float* lamA = (float*)(pos4 + TOTAL);
    float* lamB = lamA + TOTAL;
    float* lamD = lamB + TOTAL;                            // +pad
    __hip_bfloat16* Uf = (__hip_bfloat16*)(lamD + 4);      // 8*768*1408 bf16
    __hip_bfloat16* Vf = Uf + (size_t)BATCH * MROWS * KDIM;// 8*256*1408 bf16

    // ---- host: deg-10 Chebyshev fit of G(tau)=E(4tau)=2tau*tanh(2tau) ----
    const double PI = 3.14159265358979323846;
    const double T = 1.30;                 // tau range (|pre| <= 5.2)
    double cc[DEG + 1] = {0};
    const int M = 128;
    for (int m = 0; m < M; ++m) {
        const double th = PI * (m + 0.5) / M;
        const double z = cos(th);
        const double tau = T * z;
        const double g = 2.0 * tau * tanh(2.0 * tau);
        for (int k = 0; k <= DEG; ++k) cc[k] += g * cos(k * th);
    }
    for (int k = 0; k <= DEG; ++k) cc[k] *= 2.0 / M;
    cc[0] *= 0.5;
    // Chebyshev -> monomial (in z), then rescale z = tau/T
    double Tm[DEG + 1][DEG + 1] = {{0}};
    Tm[0][0] = 1; Tm[1][1] = 1;
    for (int k = 2; k <= DEG; ++k)
        for (int p = 0; p <= k; ++p)
            Tm[k][p] = 2.0 * (p > 0 ? Tm[k - 1][p - 1] : 0.0) - Tm[k - 2][p];
    double e[DEG + 1] = {0};
    {
        double tp = 1.0;
        for (int p = 0; p <= DEG; ++p) {
            double s = 0;
            for (int k = 0; k <= DEG; ++k) s += cc[k] * Tm[k][p];
            e[p] = s / tp;
            tp *= T;
        }
    }
    for (int p = 1; p <= DEG; p += 2) e[p] = 0.0;   // G is even
    // P0 = G, P1 = G', P2 = G''/2
    double P[3][DEG + 1] = {{0}};
    for (int p = 0; p <= DEG; ++p) P[0][p] = e[p];
    for (int p = 0; p <= DEG - 1; ++p) P[1][p] = (p + 1) * e[p + 1];
    for (int p = 0; p <= DEG - 2; ++p) P[2][p] = 0.5 * (p + 2) * (p + 1) * e[p + 2];
    // note: alpha2 already carries the 1/2?  alpha2 = W2*w^2/2 and P2 = G''/2
    // would double-count; use P2 = G'' here and keep 1/2 in alpha2:
    for (int p = 0; p <= DEG - 2; ++p) P[2][p] = (p + 2) * (p + 1) * e[p + 2];
    double C[NQ][NQ] = {{0}};
    for (int n = 0; n < NQ; ++n) {
        C[n][0] = 1;
        for (int k = 1; k <= n; ++k)
            C[n][k] = C[n - 1][k - 1] + (k <= n - 1 ? C[n - 1][k] : 0.0);
    }
    QC qc;
    for (int n = 0; n < 3; ++n)
        for (int q = 0; q < NQ; ++q)
            for (int p = 0; p < NQ; ++p)
                qc.v[n][q][p] =
                    (p + q <= DEG) ? (float)(P[n][p + q] * C[p + q][p]) : 0.f;

    evh_prep_kernel<<<TOTAL, HDIM, 0, stream>>>(h, W1, b1, W2, pos,
                                                Uf, Vf, pos4,
                                                lamA, lamB, lamD, out, qc);
    evh_gemm_kernel<<<48 * BATCH, 256, 0, stream>>>(Uf, Vf, X);
    evh_comb_kernel<<<BATCH * (NPTS / 2), 256, 0, stream>>>(
        X, pos4, lamA, lamB, lamD, b2, out);
}

// Round 14
// 44.985 us; speedup vs baseline: 1.6626x; 1.6626x over previous
//
#include <hip/hip_runtime.h>
#include <hip/hip_bf16.h>
#include <math.h>

#define BATCH 8
#define NPTS  256
#define HDIM  128
#define TOTAL (BATCH * NPTS)   // 2048
#define PRE_SCALE 0.25f        // tau = pre/4
#define DEG   8                // even poly degree for G(tau)=E(4*tau)
#define NQ    9                // q = 0..8
#define KDIM  (HDIM * NQ)      // 1152 = GEMM K
#define MROWS (3 * NPTS)       // 768 stacked feature rows (X0,X1,X2)
#define NKSTEP (KDIM / 64)     // 18

typedef __attribute__((ext_vector_type(8))) short short8;
typedef __attribute__((ext_vector_type(4))) float f32x4;

struct QC { float v[3][NQ][NQ]; };   // qc[n][q][p] = Pn[p+q]*C(p+q,p)

// ---------------------------------------------------------------------------
// Kernel 1: projections + lambdas + GEMM feature build + out-zero.
// (identical math to r13, NQ=9)
// ---------------------------------------------------------------------------
__global__ __launch_bounds__(HDIM) void evh_prep_kernel(
    const float* __restrict__ h, const float* __restrict__ W1,
    const float* __restrict__ b1, const float* __restrict__ W2,
    const float* __restrict__ pos,
    __hip_bfloat16* __restrict__ Uf, __hip_bfloat16* __restrict__ Vf,
    float4* __restrict__ pos4,
    float* __restrict__ lamA, float* __restrict__ lamB,
    float* __restrict__ lamD, float* __restrict__ out, QC qc)
{
    __shared__ float hrow[HDIM];
    __shared__ float sA[2], sB[2], sD[2];
    const int t = blockIdx.x;
    const int c = threadIdx.x;
    const int wv = c >> 6, ln = c & 63;
    const int b = t >> 8, jj = t & 255;
    hrow[c] = h[t * HDIM + c];
    const float w2c = W2[c];
    const float wdc = W1[2 * HDIM * HDIM + c];
    if (c < 3) out[t * 3 + c] = 0.f;
    if (c == 0)
        pos4[t] = make_float4(pos[t * 3], pos[t * 3 + 1], pos[t * 3 + 2], 0.f);
    __syncthreads();

    float a = 0.f, bsum = 0.f;
#pragma unroll 8
    for (int k = 0; k < HDIM; ++k) {
        const float hv = hrow[k];
        a    = fmaf(hv, W1[k * HDIM + c], a);
        bsum = fmaf(hv, W1[(HDIM + k) * HDIM + c], bsum);
    }
    const float bb = bsum + b1[c];

    // feature build
    const float u = a * PRE_SCALE;
    const float v = bb * PRE_SCALE;
    const float w = wdc * PRE_SCALE;
    const float alph[3] = { w2c, w2c * w, 0.5f * w2c * w * w };
    for (int n = 0; n < 3; ++n) {
        __hip_bfloat16* dst =
            Uf + ((size_t)((b * 3 + n) * NPTS + jj)) * KDIM + c * NQ;
        const float an = alph[n];
        for (int q = 0; q < NQ; ++q) {
            const int dp = DEG - q;
            float r = qc.v[n][q][dp];
            for (int p = dp - 1; p >= 0; --p) r = fmaf(r, u, qc.v[n][q][p]);
            dst[q] = __float2bfloat16(an * r);
        }
    }
    {
        __hip_bfloat16* vdst = Vf + ((size_t)(b * NPTS + jj)) * KDIM + c * NQ;
        float vp = 1.f;
        for (int q = 0; q < NQ; ++q) { vdst[q] = __float2bfloat16(vp); vp *= v; }
    }

    // exact linear-part lambdas (wave shuffles)
    float va = w2c * a, vb = w2c * bb;
#pragma unroll
    for (int off = 32; off >= 1; off >>= 1) {
        va += __shfl_xor(va, off, 64);
        vb += __shfl_xor(vb, off, 64);
    }
    if (ln == 0) { sA[wv] = va; sB[wv] = vb; }
    __syncthreads();
    if (c == 0) {
        lamA[t] = 0.5f * (sA[0] + sA[1]);
        lamB[t] = 0.5f * (sB[0] + sB[1]);
    }
    if (t == 0) {  // block-uniform branch
        float vd = w2c * wdc;
#pragma unroll
        for (int off = 32; off >= 1; off >>= 1) vd += __shfl_xor(vd, off, 64);
        if (ln == 0) sD[wv] = vd;
        __syncthreads();
        if (c == 0) lamD[0] = 0.5f * (sD[0] + sD[1]);
    }
}

// ---------------------------------------------------------------------------
// Kernel 2: batched MFMA GEMM, LDS-staged.
// X[b][n][i][j] = sum_k Uf[b][n*256+j][k] * Vf[b][i][k]
// 384 blocks (batch = blk&7 -> XCD-local), 64x64 tile, BK=64, 4 waves x
// 32x32 (2x2 16x16x32 bf16 frags). Staging: reg (uint4) -> ds_write_b128
// with chunk^=(row&7) XOR swizzle (write AND read sides); coalesced global
// reads; 1-deep register prefetch overlaps MFMA compute.
// ---------------------------------------------------------------------------
__global__ __launch_bounds__(256) void evh_gemm_kernel(
    const __hip_bfloat16* __restrict__ Uf, const __hip_bfloat16* __restrict__ Vf,
    float* __restrict__ X)
{
    __shared__ __hip_bfloat16 Alds[64 * 64];
    __shared__ __hip_bfloat16 Blds[64 * 64];

    const int blk  = blockIdx.x;
    const int b    = blk & 7;
    const int tile = blk >> 3;            // 0..47
    const int tm   = tile % 12;           // 64-row tile of M=768
    const int tn   = tile / 12;           // 64-col tile of N=256
    const int tid  = threadIdx.x;
    const int wave = tid >> 6, lane = tid & 63;
    const int mrow = lane & 15, kb = lane >> 4;

    const __hip_bfloat16* __restrict__ Ub =
        Uf + (size_t)b * MROWS * KDIM + (size_t)tm * 64 * KDIM;
    const __hip_bfloat16* __restrict__ Vb =
        Vf + (size_t)b * NPTS * KDIM + (size_t)tn * 64 * KDIM;

    const int srow = tid >> 3;            // staging row (this thread, it=0)
    const int schn = tid & 7;             // staging 16B-chunk within row

    f32x4 acc[2][2] = {};

    uint4 ra0, ra1, rb0, rb1;
#define LOADREGS(K0)                                                        \
    {                                                                       \
        const int k0_ = (K0);                                               \
        ra0 = *reinterpret_cast<const uint4*>(Ub + (size_t)srow * KDIM + k0_ + schn * 8);        \
        ra1 = *reinterpret_cast<const uint4*>(Ub + (size_t)(srow + 32) * KDIM + k0_ + schn * 8); \
        rb0 = *reinterpret_cast<const uint4*>(Vb + (size_t)srow * KDIM + k0_ + schn * 8);        \
        rb1 = *reinterpret_cast<const uint4*>(Vb + (size_t)(srow + 32) * KDIM + k0_ + schn * 8); \
    }

    LOADREGS(0)
    for (int kk = 0; kk < NKSTEP; ++kk) {
        __syncthreads();   // previous compute done; LDS reusable
        *reinterpret_cast<uint4*>(&Alds[srow * 64 + (schn ^ (srow & 7)) * 8]) = ra0;
        *reinterpret_cast<uint4*>(&Alds[(srow + 32) * 64 + (schn ^ ((srow + 32) & 7)) * 8]) = ra1;
        *reinterpret_cast<uint4*>(&Blds[srow * 64 + (schn ^ (srow & 7)) * 8]) = rb0;
        *reinterpret_cast<uint4*>(&Blds[(srow + 32) * 64 + (schn ^ ((srow + 32) & 7)) * 8]) = rb1;
        __syncthreads();   // tile ready
        if (kk + 1 < NKSTEP) LOADREGS((kk + 1) * 64)   // prefetch overlaps MFMA

        const int lmA0 = (wave >> 1) * 32 + mrow;
        const int lnB0 = (wave & 1) * 32 + mrow;
#pragma unroll
        for (int ks = 0; ks < 2; ++ks) {
            const int ch = (ks * 4 + kb);
            const short8 A0 = *reinterpret_cast<const short8*>(
                &Alds[lmA0 * 64 + (ch ^ (lmA0 & 7)) * 8]);
            const short8 A1 = *reinterpret_cast<const short8*>(
                &Alds[(lmA0 + 16) * 64 + (ch ^ (lmA0 & 7)) * 8]);
            const short8 B0 = *reinterpret_cast<const short8*>(
                &Blds[lnB0 * 64 + (ch ^ (lnB0 & 7)) * 8]);
            const short8 B1 = *reinterpret_cast<const short8*>(
                &Blds[(lnB0 + 16) * 64 + (ch ^ (lnB0 & 7)) * 8]);
            acc[0][0] = __builtin_amdgcn_mfma_f32_16x16x32_bf16(A0, B0, acc[0][0], 0, 0, 0);
            acc[0][1] = __builtin_amdgcn_mfma_f32_16x16x32_bf16(A0, B1, acc[0][1], 0, 0, 0);
            acc[1][0] = __builtin_amdgcn_mfma_f32_16x16x32_bf16(A1, B0, acc[1][0], 0, 0, 0);
            acc[1][1] = __builtin_amdgcn_mfma_f32_16x16x32_bf16(A1, B1, acc[1][1], 0, 0, 0);
        }
    }
#undef LOADREGS

    // C-write (r13-validated layout): row m -> (nfeat=m>>8, j=m&255), col -> i
    const int m0g = tm * 64 + (wave >> 1) * 32;
    const int n0g = tn * 64 + (wave & 1) * 32;
#pragma unroll
    for (int fm = 0; fm < 2; ++fm) {
#pragma unroll
        for (int fn = 0; fn < 2; ++fn) {
            const int mbase = m0g + fm * 16 + (lane >> 4) * 4;
            const int i     = n0g + fn * 16 + (lane & 15);
            const int nfeat = mbase >> 8;
            const int j0    = mbase & 255;
            float* dst = X + ((size_t)((b * 3 + nfeat) * NPTS + i)) * NPTS + j0;
            *reinterpret_cast<float4*>(dst) =
                *reinterpret_cast<float4*>(&acc[fm][fn]);
        }
    }
}

// ---------------------------------------------------------------------------
// Kernel 3: combine + v-reduction (unchanged from r13).
// ---------------------------------------------------------------------------
__global__ __launch_bounds__(256) void evh_comb_kernel(
    const float* __restrict__ X, const float4* __restrict__ pos4,
    const float* __restrict__ lamA, const float* __restrict__ lamB,
    const float* __restrict__ lamD, const float* __restrict__ b2,
    float* __restrict__ out)
{
    const int blk = blockIdx.x;                 // 0..1023
    const int b   = blk >> 7;
    const int i0  = (blk & 127) * 2;
    const int tid = threadIdx.x;                // = j
    const int brow = b * NPTS;
    const int row_j = brow + tid;

    const float4 pj  = pos4[row_j];
    const float4 pi0 = pos4[brow + i0];
    const float4 pi1 = pos4[brow + i0 + 1];
    const float dx0 = pj.x - pi0.x, dy0 = pj.y - pi0.y, dz0 = pj.z - pi0.z;
    const float dx1 = pj.x - pi1.x, dy1 = pj.y - pi1.y, dz1 = pj.z - pi1.z;
    const float d0 = sqrtf(dx0 * dx0 + dy0 * dy0 + dz0 * dz0);
    const float d1 = sqrtf(dx1 * dx1 + dy1 * dy1 + dz1 * dz1);

    const size_t xb = (size_t)(b * 3) * NPTS * NPTS;
    const float x00 = X[xb + (size_t)(0 * NPTS + i0)     * NPTS + tid];
    const float x01 = X[xb + (size_t)(0 * NPTS + i0 + 1) * NPTS + tid];
    const float x10 = X[xb + (size_t)(1 * NPTS + i0)     * NPTS + tid];
    const float x11 = X[xb + (size_t)(1 * NPTS + i0 + 1) * NPTS + tid];
    const float x20 = X[xb + (size_t)(2 * NPTS + i0)     * NPTS + tid];
    const float x21 = X[xb + (size_t)(2 * NPTS + i0 + 1) * NPTS + tid];

    const float la = lamA[row_j];
    const float ld = lamD[0];
    const float bv = b2[0];
    const float c0 = la + lamB[brow + i0]     + d0 * ld + bv
                     + x00 + d0 * x10 + d0 * d0 * x20;
    const float c1 = la + lamB[brow + i0 + 1] + d1 * ld + bv
                     + x01 + d1 * x11 + d1 * d1 * x21;

    const int wave = tid >> 6, lane = tid & 63;
    float v0x = c0 * dx0, v0y = c0 * dy0, v0z = c0 * dz0;
    float v1x = c1 * dx1, v1y = c1 * dy1, v1z = c1 * dz1;
#pragma unroll
    for (int off = 32; off >= 1; off >>= 1) {
        v0x += __shfl_xor(v0x, off, 64);
        v0y += __shfl_xor(v0y, off, 64);
        v0z += __shfl_xor(v0z, off, 64);
        v1x += __shfl_xor(v1x, off, 64);
        v1y += __shfl_xor(v1y, off, 64);
        v1z += __shfl_xor(v1z, off, 64);
    }
    __shared__ float vsh[4][6];
    if (lane == 0) {
        vsh[wave][0] = v0x; vsh[wave][1] = v0y; vsh[wave][2] = v0z;
        vsh[wave][3] = v1x; vsh[wave][4] = v1y; vsh[wave][5] = v1z;
    }
    __syncthreads();
    if (tid < 6) {
        const float val = vsh[0][tid] + vsh[1][tid] + vsh[2][tid] + vsh[3][tid];
        const int s = tid / 3, comp = tid % 3;
        atomicAdd(&out[(brow + i0 + s) * 3 + comp], val);
    }
}

extern "C" void kernel_launch(void* const* d_in, const int* in_sizes, int n_in,
                              void* d_out, int out_size, void* d_ws, size_t ws_size,
                              hipStream_t stream) {
    const float* h   = (const float*)d_in[0];
    const float* pos = (const float*)d_in[1];
    const float* W1  = (const float*)d_in[3];
    const float* b1  = (const float*)d_in[4];
    const float* W2  = (const float*)d_in[5];
    const float* b2  = (const float*)d_in[6];
    float* out = (float*)d_out;

    // workspace layout (~25.2 MB)
    float* X = (float*)d_ws;                               // 8*3*256*256 f32
    float4* pos4 = (float4*)(X + (size_t)BATCH * 3 * NPTS * NPTS);
    float* lamA = (float*)(pos4 + TOTAL);
    float* lamB = lamA + TOTAL;
    float* lamD = lamB + TOTAL;                            // +pad
    __hip_bfloat16* Uf = (__hip_bfloat16*)(lamD + 4);      // 8*768*1152 bf16
    __hip_bfloat16* Vf = Uf + (size_t)BATCH * MROWS * KDIM;// 8*256*1152 bf16

    // ---- host: deg-8 Chebyshev fit of G(tau)=E(4tau)=2tau*tanh(2tau) ----
    const double PI = 3.14159265358979323846;
    const double T = 1.30;                 // tau range (|pre| <= 5.2)
    double cc[DEG + 1] = {0};
    const int M = 128;
    for (int m = 0; m < M; ++m) {
        const double th = PI * (m + 0.5) / M;
        const double z = cos(th);
        const double tau = T * z;
        const double g = 2.0 * tau * tanh(2.0 * tau);
        for (int k = 0; k <= DEG; ++k) cc[k] += g * cos(k * th);
    }
    for (int k = 0; k <= DEG; ++k) cc[k] *= 2.0 / M;
    cc[0] *= 0.5;
    // Chebyshev -> monomial (in z), then rescale z = tau/T
    double Tm[DEG + 1][DEG + 1] = {{0}};
    Tm[0][0] = 1; Tm[1][1] = 1;
    for (int k = 2; k <= DEG; ++k)
        for (int p = 0; p <= k; ++p)
            Tm[k][p] = 2.0 * (p > 0 ? Tm[k - 1][p - 1] : 0.0) - Tm[k - 2][p];
    double e[DEG + 1] = {0};
    {
        double tp = 1.0;
        for (int p = 0; p <= DEG; ++p) {
            double s = 0;
            for (int k = 0; k <= DEG; ++k) s += cc[k] * Tm[k][p];
            e[p] = s / tp;
            tp *= T;
        }
    }
    for (int p = 1; p <= DEG; p += 2) e[p] = 0.0;   // G is even
    // P0 = G, P1 = G', P2 = G''  (alpha2 carries the 1/2)
    double P[3][DEG + 1] = {{0}};
    for (int p = 0; p <= DEG; ++p) P[0][p] = e[p];
    for (int p = 0; p <= DEG - 1; ++p) P[1][p] = (p + 1) * e[p + 1];
    for (int p = 0; p <= DEG - 2; ++p) P[2][p] = (p + 2) * (p + 1) * e[p + 2];
    double C[NQ][NQ] = {{0}};
    for (int n = 0; n < NQ; ++n) {
        C[n][0] = 1;
        for (int k = 1; k <= n; ++k)
            C[n][k] = C[n - 1][k - 1] + (k <= n - 1 ? C[n - 1][k] : 0.0);
    }
    QC qc;
    for (int n = 0; n < 3; ++n)
        for (int q = 0; q < NQ; ++q)
            for (int p = 0; p < NQ; ++p)
                qc.v[n][q][p] =
                    (p + q <= DEG) ? (float)(P[n][p + q] * C[p + q][p]) : 0.f;

    evh_prep_kernel<<<TOTAL, HDIM, 0, stream>>>(h, W1, b1, W2, pos,
                                                Uf, Vf, pos4,
                                                lamA, lamB, lamD, out, qc);
    evh_gemm_kernel<<<48 * BATCH, 256, 0, stream>>>(Uf, Vf, X);
    evh_comb_kernel<<<BATCH * (NPTS / 2), 256, 0, stream>>>(
        X, pos4, lamA, lamB, lamD, b2, out);
}

// Round 15
// 34.102 us; speedup vs baseline: 2.1932x; 1.3191x over previous
//
#include <hip/hip_runtime.h>
#include <math.h>

#define BATCH 8
#define NPTS  256
#define HDIM  128
#define TOTAL (BATCH * NPTS)   // 2048
#define PRE_SCALE 0.25f        // t = pre/4; y = t^2 - 1 in [-1,1] for |pre|<=5.66

// ---------------------------------------------------------------------------
// Kernel 1 (identical to r11 champion): projections + scale folding +
// linear-part lambdas + out-zeroing.
//   A'[t,c]  = (h@Wa)[t,c] * PRE_SCALE    quad-interleaved channel-major
//   Bb'[t,c] = ((h@Wb)[t,c]+b1[c]) * PRE_SCALE
//   wdx[c] = W1[2H,c]*PRE_SCALE,  w2x[c] = W2[c]
//   lamA/lamB/lamD = exact linear (odd) part of silu.
// ---------------------------------------------------------------------------
__global__ __launch_bounds__(HDIM) void evh_prep_kernel(
    const float* __restrict__ h, const float* __restrict__ W1,
    const float* __restrict__ b1, const float* __restrict__ W2,
    float* __restrict__ A_T4, float* __restrict__ Bb,
    float* __restrict__ wdx, float* __restrict__ w2x,
    float* __restrict__ lamA, float* __restrict__ lamB,
    float* __restrict__ lamD, float* __restrict__ out)
{
    __shared__ float hrow[HDIM];
    __shared__ float sA[2], sB[2], sD[2];
    const int t = blockIdx.x;
    const int c = threadIdx.x;
    const int wv = c >> 6, ln = c & 63;
    hrow[c] = h[t * HDIM + c];
    const float w2c = W2[c];
    const float wdc = W1[2 * HDIM * HDIM + c];
    if (t == 0) {
        wdx[c] = wdc * PRE_SCALE;
        w2x[c] = w2c;
    }
    if (c < 3) out[t * 3 + c] = 0.f;
    __syncthreads();

    float a = 0.f, bsum = 0.f;
#pragma unroll 8
    for (int k = 0; k < HDIM; ++k) {
        const float hv = hrow[k];
        a    = fmaf(hv, W1[k * HDIM + c], a);
        bsum = fmaf(hv, W1[(HDIM + k) * HDIM + c], bsum);
    }
    const float bb = bsum + b1[c];
    A_T4[(c >> 2) * (4 * TOTAL) + 4 * t + (c & 3)] = a * PRE_SCALE;
    Bb[(size_t)t * HDIM + c] = bb * PRE_SCALE;

    float va = w2c * a, vb = w2c * bb;
#pragma unroll
    for (int off = 32; off >= 1; off >>= 1) {
        va += __shfl_xor(va, off, 64);
        vb += __shfl_xor(vb, off, 64);
    }
    if (ln == 0) { sA[wv] = va; sB[wv] = vb; }
    __syncthreads();
    if (c == 0) {
        lamA[t] = 0.5f * (sA[0] + sA[1]);
        lamB[t] = 0.5f * (sB[0] + sB[1]);
    }

    if (t == 0) {  // block-uniform branch: barriers legal
        float vd = w2c * wdc;
#pragma unroll
        for (int off = 32; off >= 1; off >>= 1) vd += __shfl_xor(vd, off, 64);
        if (ln == 0) sD[wv] = vd;
        __syncthreads();
        if (c == 0) lamD[0] = 0.5f * (sD[0] + sD[1]);
    }
}

// ---------------------------------------------------------------------------
// Kernel 2: pairwise pass = r11 champion + (a) one-shot LDS staging of the
// 256 uniform floats (bb0,bb1,wd,w2; broadcast ds_read_b128 in-loop, no
// global uniform streams), (b) explicit 2-stage A prefetch (4 float4 ahead)
// so L2 latency hides under the previous group's 32 cells of fma.
// Cell math: deg-4 even poly (8 f32 ops/cell), exact linear part via lambdas.
// ---------------------------------------------------------------------------
__global__ __launch_bounds__(256, 8) void evh_pair_kernel(
    const float* __restrict__ A_T4, const float* __restrict__ Bb,
    const float* __restrict__ wdx, const float* __restrict__ w2x,
    const float* __restrict__ lamA, const float* __restrict__ lamB,
    const float* __restrict__ lamD,
    const float* __restrict__ pos, const float* __restrict__ b2,
    float* __restrict__ out,
    float q0, float q1, float q2, float q3, float q4)
{
    const int blk = blockIdx.x;                 // 0..2047
    const int ch  = blk & 1;                    // channel half
    const int b   = blk >> 8;                   // batch
    const int i0  = ((blk >> 1) & 127) * 2;     // target pair base
    const int tid = threadIdx.x;                // = j within batch
    const int brow  = b * NPTS;
    const int row_j = brow + tid;

    // ---- stage the 4 uniform streams into LDS: 1 float per thread ----
    __shared__ float ubb0[64], ubb1[64], uwd[64], uw2[64];
    {
        const int grp = tid >> 6;   // 0..3
        const int l   = tid & 63;
        const float* __restrict__ bb0p = Bb + (size_t)(brow + i0) * HDIM + ch * 64;
        if      (grp == 0) ubb0[l] = bb0p[l];
        else if (grp == 1) ubb1[l] = bb0p[HDIM + l];
        else if (grp == 2) uwd[l]  = wdx[ch * 64 + l];
        else               uw2[l]  = w2x[ch * 64 + l];
    }

    const float pjx = pos[row_j * 3 + 0];
    const float pjy = pos[row_j * 3 + 1];
    const float pjz = pos[row_j * 3 + 2];

    float dx0, dy0, dz0, dist0, dx1, dy1, dz1, dist1;
    {
        const int r0 = brow + i0, r1 = r0 + 1;
        dx0 = pjx - pos[r0 * 3 + 0];
        dy0 = pjy - pos[r0 * 3 + 1];
        dz0 = pjz - pos[r0 * 3 + 2];
        dist0 = sqrtf(dx0 * dx0 + dy0 * dy0 + dz0 * dz0);
        dx1 = pjx - pos[r1 * 3 + 0];
        dy1 = pjy - pos[r1 * 3 + 1];
        dz1 = pjz - pos[r1 * 3 + 2];
        dist1 = sqrtf(dx1 * dx1 + dy1 * dy1 + dz1 * dz1);
    }
    __syncthreads();   // uniforms staged

    const float* __restrict__ ap = A_T4 + 4 * row_j
                                   + (size_t)(ch * 16) * (4 * TOTAL);

    float acc0 = 0.f, acc1 = 0.f;

#define CELL(AK, BK, WDK, W2K, D01)                                     \
    {                                                                   \
        const float t0 = fmaf(dist0, (WDK), (AK) + (BK##0));            \
        const float t1 = fmaf(dist1, (WDK), (AK) + (BK##1));            \
        const float y0 = fmaf(t0, t0, -1.0f);                           \
        const float y1 = fmaf(t1, t1, -1.0f);                           \
        float r0 = fmaf(q4, y0, q3), r1 = fmaf(q4, y1, q3);             \
        r0 = fmaf(r0, y0, q2);  r1 = fmaf(r1, y1, q2);                  \
        r0 = fmaf(r0, y0, q1);  r1 = fmaf(r1, y1, q1);                  \
        r0 = fmaf(r0, y0, q0);  r1 = fmaf(r1, y1, q0);                  \
        acc0 = fmaf((W2K), r0, acc0);                                   \
        acc1 = fmaf((W2K), r1, acc1);                                   \
    }

    // 4 groups of 4 quads; 2-stage register prefetch of the A stream.
    float4 pa0, pa1, pa2, pa3;      // current group
    float4 na0, na1, na2, na3;      // next group
#define LOADG(V0, V1, V2, V3, G)                                        \
    {                                                                   \
        const float* gp = ap + (size_t)(G) * 4 * (4 * TOTAL);           \
        V0 = *reinterpret_cast<const float4*>(gp + 0 * (4 * TOTAL));    \
        V1 = *reinterpret_cast<const float4*>(gp + 1 * (4 * TOTAL));    \
        V2 = *reinterpret_cast<const float4*>(gp + 2 * (4 * TOTAL));    \
        V3 = *reinterpret_cast<const float4*>(gp + 3 * (4 * TOTAL));    \
    }
#define COMPG(V0, V1, V2, V3, G)                                        \
    {                                                                   \
        _Pragma("unroll")                                               \
        for (int qq = 0; qq < 4; ++qq) {                                \
            const int q = (G) * 4 + qq;                                 \
            const float4 bb0 = *reinterpret_cast<const float4*>(&ubb0[4 * q]); \
            const float4 bb1 = *reinterpret_cast<const float4*>(&ubb1[4 * q]); \
            const float4 wd  = *reinterpret_cast<const float4*>(&uwd[4 * q]);  \
            const float4 w2  = *reinterpret_cast<const float4*>(&uw2[4 * q]);  \
            const float4 av = (qq == 0) ? V0 : (qq == 1) ? V1           \
                             : (qq == 2) ? V2 : V3;                     \
            CELL(av.x, bb0.x + 0 * bb1.x, wd.x, w2.x, )                 \
            CELL(av.y, bb0.y + 0 * bb1.y, wd.y, w2.y, )                 \
            CELL(av.z, bb0.z + 0 * bb1.z, wd.z, w2.z, )                 \
            CELL(av.w, bb0.w + 0 * bb1.w, wd.w, w2.w, )                 \
        }                                                               \
    }
    // NOTE: the CELL macro uses BK##0 / BK##1 token pasting; feed it the
    // pair via named locals instead of the COMPG hack above.
#undef COMPG
#define COMPG(V0, V1, V2, V3, G)                                        \
    {                                                                   \
        _Pragma("unroll")                                               \
        for (int qq = 0; qq < 4; ++qq) {                                \
            const int q = (G) * 4 + qq;                                 \
            const float4 u0 = *reinterpret_cast<const float4*>(&ubb0[4 * q]); \
            const float4 u1 = *reinterpret_cast<const float4*>(&ubb1[4 * q]); \
            const float4 wd = *reinterpret_cast<const float4*>(&uwd[4 * q]);  \
            const float4 w2 = *reinterpret_cast<const float4*>(&uw2[4 * q]);  \
            const float4 av = (qq == 0) ? V0 : (qq == 1) ? V1           \
                             : (qq == 2) ? V2 : V3;                     \
            const float bx0 = u0.x, bx1 = u1.x;                         \
            const float by0 = u0.y, by1 = u1.y;                         \
            const float bz0 = u0.z, bz1 = u1.z;                         \
            const float bw0 = u0.w, bw1 = u1.w;                         \
            CELL(av.x, bx, wd.x, w2.x, )                                \
            CELL(av.y, by, wd.y, w2.y, )                                \
            CELL(av.z, bz, wd.z, w2.z, )                                \
            CELL(av.w, bw, wd.w, w2.w, )                                \
        }                                                               \
    }

    LOADG(pa0, pa1, pa2, pa3, 0)
    LOADG(na0, na1, na2, na3, 1)        // prefetch group 1
    COMPG(pa0, pa1, pa2, pa3, 0)
    LOADG(pa0, pa1, pa2, pa3, 2)        // prefetch group 2
    COMPG(na0, na1, na2, na3, 1)
    LOADG(na0, na1, na2, na3, 3)        // prefetch group 3
    COMPG(pa0, pa1, pa2, pa3, 2)
    COMPG(na0, na1, na2, na3, 3)
#undef LOADG
#undef COMPG
#undef CELL

    // exact linear part + b2, contributed once (ch 0)
    float c0 = acc0, c1 = acc1;
    if (ch == 0) {
        const float la = lamA[row_j];
        const float ld = lamD[0];
        const float bv = b2[0];
        c0 += la + lamB[brow + i0]     + dist0 * ld + bv;
        c1 += la + lamB[brow + i0 + 1] + dist1 * ld + bv;
    }

    const int wave = tid >> 6;
    const int lane = tid & 63;
    float v0x = c0 * dx0, v0y = c0 * dy0, v0z = c0 * dz0;
    float v1x = c1 * dx1, v1y = c1 * dy1, v1z = c1 * dz1;
#pragma unroll
    for (int off = 32; off >= 1; off >>= 1) {
        v0x += __shfl_xor(v0x, off, 64);
        v0y += __shfl_xor(v0y, off, 64);
        v0z += __shfl_xor(v0z, off, 64);
        v1x += __shfl_xor(v1x, off, 64);
        v1y += __shfl_xor(v1y, off, 64);
        v1z += __shfl_xor(v1z, off, 64);
    }

    __shared__ float vsh[4][6];
    if (lane == 0) {
        vsh[wave][0] = v0x; vsh[wave][1] = v0y; vsh[wave][2] = v0z;
        vsh[wave][3] = v1x; vsh[wave][4] = v1y; vsh[wave][5] = v1z;
    }
    __syncthreads();
    if (tid < 6) {
        const float val = vsh[0][tid] + vsh[1][tid] + vsh[2][tid] + vsh[3][tid];
        const int s = tid / 3, comp = tid % 3;
        atomicAdd(&out[(brow + i0 + s) * 3 + comp], val);
    }
}

extern "C" void kernel_launch(void* const* d_in, const int* in_sizes, int n_in,
                              void* d_out, int out_size, void* d_ws, size_t ws_size,
                              hipStream_t stream) {
    const float* h   = (const float*)d_in[0];  // (2048, 128)
    const float* pos = (const float*)d_in[1];  // (2048, 3)
    // d_in[2] = batch indices (int64) — contiguous per batch, unused
    const float* W1  = (const float*)d_in[3];  // (257, 128)
    const float* b1  = (const float*)d_in[4];  // (128,)
    const float* W2  = (const float*)d_in[5];  // (128, 1)
    const float* b2  = (const float*)d_in[6];  // (1,)
    float* out = (float*)d_out;                // (2048, 3)

    float* A_T4 = (float*)d_ws;                // 1 MB
    float* Bb   = A_T4 + (size_t)TOTAL * HDIM; // 1 MB
    float* wdx  = Bb + (size_t)TOTAL * HDIM;   // 512 B
    float* w2x  = wdx + HDIM;                  // 512 B
    float* lamA = w2x + HDIM;                  // 8 KB
    float* lamB = lamA + TOTAL;                // 8 KB
    float* lamD = lamB + TOTAL;                // 4 B

    // Host-side degree-4 Chebyshev fit of E(pre) = (pre/2)*tanh(pre/2) as a
    // polynomial in y = (pre*PRE_SCALE)^2 - 1  (covers |pre| <= 5.66).
    const double PI = 3.14159265358979323846;
    double cc[5] = {0, 0, 0, 0, 0};
    const int M = 64;
    for (int m = 0; m < M; ++m) {
        const double th = PI * (m + 0.5) / M;
        const double yp = cos(th);
        const double s  = 16.0 * (1.0 + yp);   // pre^2 in [0, 32]
        const double x  = sqrt(s > 0 ? s : 0);
        const double f  = 0.5 * x * tanh(0.5 * x);
        for (int k = 0; k < 5; ++k) cc[k] += f * cos(k * th);
    }
    for (int k = 0; k < 5; ++k) cc[k] *= 2.0 / M;
    cc[0] *= 0.5;
    const double p0 = cc[0] - cc[2] + cc[4];
    const double p1 = cc[1] - 3 * cc[3];
    const double p2 = 2 * cc[2] - 8 * cc[4];
    const double p3 = 4 * cc[3];
    const double p4 = 8 * cc[4];

    evh_prep_kernel<<<TOTAL, HDIM, 0, stream>>>(h, W1, b1, W2,
                                                A_T4, Bb, wdx, w2x,
                                                lamA, lamB, lamD, out);
    evh_pair_kernel<<<TOTAL, 256, 0, stream>>>(A_T4, Bb, wdx, w2x,
                                               lamA, lamB, lamD,
                                               pos, b2, out,
                                               (float)p0, (float)p1, (float)p2,
                                               (float)p3, (float)p4);
}

// Round 16
// 30.581 us; speedup vs baseline: 2.4456x; 1.1151x over previous
//
#include <hip/hip_runtime.h>
#include <math.h>

#define BATCH 8
#define NPTS  256
#define HDIM  128
#define TOTAL (BATCH * NPTS)   // 2048
#define PRE_SCALE 0.25f        // t = pre/4; y = t^2 - 1 in [-1,1] for |pre|<=5.66

// ---------------------------------------------------------------------------
// Kernel 1 (r11 champion, minus out-zeroing): projections + scale folding +
// linear-part lambdas.
//   A'[t,c]  = (h@Wa)[t,c] * PRE_SCALE    quad-interleaved channel-major
//   Bb'[t,c] = ((h@Wb)[t,c]+b1[c]) * PRE_SCALE
//   wdx[c] = W1[2H,c]*PRE_SCALE,  w2x[c] = W2[c]
//   lamA/lamB/lamD = exact linear (odd) part of silu.
// ---------------------------------------------------------------------------
__global__ __launch_bounds__(HDIM) void evh_prep_kernel(
    const float* __restrict__ h, const float* __restrict__ W1,
    const float* __restrict__ b1, const float* __restrict__ W2,
    float* __restrict__ A_T4, float* __restrict__ Bb,
    float* __restrict__ wdx, float* __restrict__ w2x,
    float* __restrict__ lamA, float* __restrict__ lamB,
    float* __restrict__ lamD)
{
    __shared__ float hrow[HDIM];
    __shared__ float sA[2], sB[2], sD[2];
    const int t = blockIdx.x;
    const int c = threadIdx.x;
    const int wv = c >> 6, ln = c & 63;
    hrow[c] = h[t * HDIM + c];
    const float w2c = W2[c];
    const float wdc = W1[2 * HDIM * HDIM + c];
    if (t == 0) {
        wdx[c] = wdc * PRE_SCALE;
        w2x[c] = w2c;
    }
    __syncthreads();

    float a = 0.f, bsum = 0.f;
#pragma unroll 8
    for (int k = 0; k < HDIM; ++k) {
        const float hv = hrow[k];
        a    = fmaf(hv, W1[k * HDIM + c], a);
        bsum = fmaf(hv, W1[(HDIM + k) * HDIM + c], bsum);
    }
    const float bb = bsum + b1[c];
    A_T4[(c >> 2) * (4 * TOTAL) + 4 * t + (c & 3)] = a * PRE_SCALE;
    Bb[(size_t)t * HDIM + c] = bb * PRE_SCALE;

    float va = w2c * a, vb = w2c * bb;
#pragma unroll
    for (int off = 32; off >= 1; off >>= 1) {
        va += __shfl_xor(va, off, 64);
        vb += __shfl_xor(vb, off, 64);
    }
    if (ln == 0) { sA[wv] = va; sB[wv] = vb; }
    __syncthreads();
    if (c == 0) {
        lamA[t] = 0.5f * (sA[0] + sA[1]);
        lamB[t] = 0.5f * (sB[0] + sB[1]);
    }

    if (t == 0) {  // block-uniform branch: barriers legal
        float vd = w2c * wdc;
#pragma unroll
        for (int off = 32; off >= 1; off >>= 1) vd += __shfl_xor(vd, off, 64);
        if (ln == 0) sD[wv] = vd;
        __syncthreads();
        if (c == 0) lamD[0] = 0.5f * (sD[0] + sD[1]);
    }
}

// ---------------------------------------------------------------------------
// Kernel 2: pairwise pass, NO channel split. Block = (batch b, target pair
// i0..i0+1). 1024 blocks x 256 threads = source j; each thread does 2 i's x
// 128 channels = 256 cells. One block owns each output pair -> direct store
// (no atomics, no out-zeroing). r11's cell math (deg-4 even poly, 8 f32
// ops/cell) and block-uniform scalar-load uniform streams, verbatim.
// __launch_bounds__(256,4): 128-VGPR budget = resident 16 waves/CU exactly.
// ---------------------------------------------------------------------------
__global__ __launch_bounds__(256, 4) void evh_pair_kernel(
    const float* __restrict__ A_T4, const float* __restrict__ Bb,
    const float* __restrict__ wdx, const float* __restrict__ w2x,
    const float* __restrict__ lamA, const float* __restrict__ lamB,
    const float* __restrict__ lamD,
    const float* __restrict__ pos, const float* __restrict__ b2,
    float* __restrict__ out,
    float q0, float q1, float q2, float q3, float q4)
{
    const int blk = blockIdx.x;                 // 0..1023
    const int b   = blk >> 7;                   // batch
    const int i0  = (blk & 127) * 2;            // target pair base
    const int tid = threadIdx.x;                // = j within batch
    const int brow  = b * NPTS;
    const int row_j = brow + tid;

    const float pjx = pos[row_j * 3 + 0];
    const float pjy = pos[row_j * 3 + 1];
    const float pjz = pos[row_j * 3 + 2];

    float dx0, dy0, dz0, dist0, dx1, dy1, dz1, dist1;
    {
        const int r0 = brow + i0, r1 = r0 + 1;
        dx0 = pjx - pos[r0 * 3 + 0];
        dy0 = pjy - pos[r0 * 3 + 1];
        dz0 = pjz - pos[r0 * 3 + 2];
        dist0 = sqrtf(dx0 * dx0 + dy0 * dy0 + dz0 * dz0);
        dx1 = pjx - pos[r1 * 3 + 0];
        dy1 = pjy - pos[r1 * 3 + 1];
        dz1 = pjz - pos[r1 * 3 + 2];
        dist1 = sqrtf(dx1 * dx1 + dy1 * dy1 + dz1 * dz1);
    }

    // block-uniform operand pointers (scalar-load friendly), full 128 ch
    const float* __restrict__ bb0p = Bb + (size_t)(brow + i0) * HDIM;
    const float* __restrict__ bb1p = bb0p + HDIM;
    const float* __restrict__ ap   = A_T4 + 4 * row_j;

    float acc0 = 0.f, acc1 = 0.f;

#define CELL(AK, BK0, BK1, WDK, W2K)                                    \
    {                                                                   \
        const float t0 = fmaf(dist0, (WDK), (AK) + (BK0));              \
        const float t1 = fmaf(dist1, (WDK), (AK) + (BK1));              \
        const float y0 = fmaf(t0, t0, -1.0f);                           \
        const float y1 = fmaf(t1, t1, -1.0f);                           \
        float r0 = fmaf(q4, y0, q3), r1 = fmaf(q4, y1, q3);             \
        r0 = fmaf(r0, y0, q2);  r1 = fmaf(r1, y1, q2);                  \
        r0 = fmaf(r0, y0, q1);  r1 = fmaf(r1, y1, q1);                  \
        r0 = fmaf(r0, y0, q0);  r1 = fmaf(r1, y1, q0);                  \
        acc0 = fmaf((W2K), r0, acc0);                                   \
        acc1 = fmaf((W2K), r1, acc1);                                   \
    }

#pragma unroll 8
    for (int q = 0; q < 32; ++q) {
        const float4 a  = *reinterpret_cast<const float4*>(
                              ap + (size_t)q * (4 * TOTAL));
        const float4 b0 = *reinterpret_cast<const float4*>(bb0p + 4 * q);
        const float4 b1 = *reinterpret_cast<const float4*>(bb1p + 4 * q);
        const float4 wd = *reinterpret_cast<const float4*>(wdx + 4 * q);
        const float4 w2 = *reinterpret_cast<const float4*>(w2x + 4 * q);

        CELL(a.x, b0.x, b1.x, wd.x, w2.x)
        CELL(a.y, b0.y, b1.y, wd.y, w2.y)
        CELL(a.z, b0.z, b1.z, wd.z, w2.z)
        CELL(a.w, b0.w, b1.w, wd.w, w2.w)
    }
#undef CELL

    // exact linear part + b2 (single owner block: unconditional)
    const float la = lamA[row_j];
    const float ld = lamD[0];
    const float bv = b2[0];
    const float c0 = acc0 + la + lamB[brow + i0]     + dist0 * ld + bv;
    const float c1 = acc1 + la + lamB[brow + i0 + 1] + dist1 * ld + bv;

    const int wave = tid >> 6;
    const int lane = tid & 63;
    float v0x = c0 * dx0, v0y = c0 * dy0, v0z = c0 * dz0;
    float v1x = c1 * dx1, v1y = c1 * dy1, v1z = c1 * dz1;
#pragma unroll
    for (int off = 32; off >= 1; off >>= 1) {
        v0x += __shfl_xor(v0x, off, 64);
        v0y += __shfl_xor(v0y, off, 64);
        v0z += __shfl_xor(v0z, off, 64);
        v1x += __shfl_xor(v1x, off, 64);
        v1y += __shfl_xor(v1y, off, 64);
        v1z += __shfl_xor(v1z, off, 64);
    }

    __shared__ float vsh[4][6];
    if (lane == 0) {
        vsh[wave][0] = v0x; vsh[wave][1] = v0y; vsh[wave][2] = v0z;
        vsh[wave][3] = v1x; vsh[wave][4] = v1y; vsh[wave][5] = v1z;
    }
    __syncthreads();
    if (tid < 6) {
        const float val = vsh[0][tid] + vsh[1][tid] + vsh[2][tid] + vsh[3][tid];
        const int s = tid / 3, comp = tid % 3;
        out[(brow + i0 + s) * 3 + comp] = val;     // direct store, no atomic
    }
}

extern "C" void kernel_launch(void* const* d_in, const int* in_sizes, int n_in,
                              void* d_out, int out_size, void* d_ws, size_t ws_size,
                              hipStream_t stream) {
    const float* h   = (const float*)d_in[0];  // (2048, 128)
    const float* pos = (const float*)d_in[1];  // (2048, 3)
    // d_in[2] = batch indices (int64) — contiguous per batch, unused
    const float* W1  = (const float*)d_in[3];  // (257, 128)
    const float* b1  = (const float*)d_in[4];  // (128,)
    const float* W2  = (const float*)d_in[5];  // (128, 1)
    const float* b2  = (const float*)d_in[6];  // (1,)
    float* out = (float*)d_out;                // (2048, 3)

    float* A_T4 = (float*)d_ws;                // 1 MB
    float* Bb   = A_T4 + (size_t)TOTAL * HDIM; // 1 MB
    float* wdx  = Bb + (size_t)TOTAL * HDIM;   // 512 B
    float* w2x  = wdx + HDIM;                  // 512 B
    float* lamA = w2x + HDIM;                  // 8 KB
    float* lamB = lamA + TOTAL;                // 8 KB
    float* lamD = lamB + TOTAL;                // 4 B

    // Host-side degree-4 Chebyshev fit of E(pre) = (pre/2)*tanh(pre/2) as a
    // polynomial in y = (pre*PRE_SCALE)^2 - 1  (covers |pre| <= 5.66).
    const double PI = 3.14159265358979323846;
    double cc[5] = {0, 0, 0, 0, 0};
    const int M = 64;
    for (int m = 0; m < M; ++m) {
        const double th = PI * (m + 0.5) / M;
        const double yp = cos(th);
        const double s  = 16.0 * (1.0 + yp);   // pre^2 in [0, 32]
        const double x  = sqrt(s > 0 ? s : 0);
        const double f  = 0.5 * x * tanh(0.5 * x);
        for (int k = 0; k < 5; ++k) cc[k] += f * cos(k * th);
    }
    for (int k = 0; k < 5; ++k) cc[k] *= 2.0 / M;
    cc[0] *= 0.5;
    const double p0 = cc[0] - cc[2] + cc[4];
    const double p1 = cc[1] - 3 * cc[3];
    const double p2 = 2 * cc[2] - 8 * cc[4];
    const double p3 = 4 * cc[3];
    const double p4 = 8 * cc[4];

    evh_prep_kernel<<<TOTAL, HDIM, 0, stream>>>(h, W1, b1, W2,
                                                A_T4, Bb, wdx, w2x,
                                                lamA, lamB, lamD);
    evh_pair_kernel<<<BATCH * (NPTS / 2), 256, 0, stream>>>(
        A_T4, Bb, wdx, w2x, lamA, lamB, lamD, pos, b2, out,
        (float)p0, (float)p1, (float)p2, (float)p3, (float)p4);
}